// Round 14
// baseline (46.098 us; speedup 1.0000x reference)
//
#include <hip/hip_runtime.h>
#include <hip/hip_bf16.h>
#include <math.h>

#define BATCH  16384
#define XDIM   18
#define LATENT 16
#define NM     128
#define KDIM   4096
#define OUTF   64
#define KB     32
#define BM     64

#define LDS_BYTES 147968   // bhs 16896 B + part 131072 B

typedef short s16x8 __attribute__((ext_vector_type(8)));
typedef float f32x16 __attribute__((ext_vector_type(16)));

__device__ __forceinline__ unsigned short f2bf(float f) {
    union { float f; unsigned u; } v; v.f = f;
    return (unsigned short)((v.u + 0x7FFFu + ((v.u >> 16) & 1u)) >> 16);
}
__device__ __forceinline__ unsigned pack_bf2(float a, float b) {
    __hip_bfloat162 h = __float22bfloat162_rn(make_float2(a, b));  // v_cvt_pk_bf16_f32
    return *(unsigned*)&h;
}
// swap bits 2 and 3 (the sigma' map: hacc C-row -> k index) — HW-verified r4-r12
__device__ __forceinline__ int swap23(int m) {
    return (m & ~12) | ((m & 4) << 1) | ((m & 8) >> 1);
}

// ---------------------------------------------------------------------------
// Precompute (unchanged, proven r4-r12): W_eff -> wfrag (B-frag layout),
// fc1_w -> f1frag (A-frag layout, sigma-permuted cols), fc1_b -> bh
// (hacc/C-layout, sigma-permuted), b_eff.
// wfrag:  [kc 0..255][ct 0..3][lane 0..63][8 bf16]
// f1frag: [jt 0..127][lane 0..63][8 bf16]
// ---------------------------------------------------------------------------
__global__ __launch_bounds__(128) void precompute_kernel(
    const float* __restrict__ x, const float* __restrict__ fc1_w,
    const float* __restrict__ fc1_b, const float* __restrict__ fc2_w,
    const float* __restrict__ fc2_b, const float* __restrict__ dil,
    const float* __restrict__ shf, unsigned short* __restrict__ wfrag,
    unsigned short* __restrict__ f1frag, float* __restrict__ bh,
    float* __restrict__ beff)
{
    const int tid = threadIdx.x;
    const int bid = blockIdx.x;
    if (bid < 512) {
        __shared__ float basis[KB];
        __shared__ float bred[32];
        if (tid < KB) {
            const float s   = x[(size_t)(BATCH - 1) * XDIM + 1];
            const float arg = s * dil[0] + shf[0];
            const float n   = 16.0f * (float)(tid & 15) / 15.0f;
            const float a   = arg * n;
            basis[tid] = (tid < 16) ? cosf(a) : sinf(a);
        }
        __syncthreads();
        const int m  = bid >> 2, kq = bid & 3;
        const int k8 = kq * 128 + tid;
        const int k  = k8 * 8;
        float acc[8] = {0.f,0.f,0.f,0.f,0.f,0.f,0.f,0.f};
        const float* src = fc2_w + (size_t)m * KB * KDIM + k;
        #pragma unroll 4
        for (int kb = 0; kb < KB; ++kb) {
            const float wgt = basis[kb];
            const float4 a = *(const float4*)(src + (size_t)kb * KDIM);
            const float4 b = *(const float4*)(src + (size_t)kb * KDIM + 4);
            acc[0] = fmaf(wgt, a.x, acc[0]); acc[1] = fmaf(wgt, a.y, acc[1]);
            acc[2] = fmaf(wgt, a.z, acc[2]); acc[3] = fmaf(wgt, a.w, acc[3]);
            acc[4] = fmaf(wgt, b.x, acc[4]); acc[5] = fmaf(wgt, b.y, acc[5]);
            acc[6] = fmaf(wgt, b.z, acc[6]); acc[7] = fmaf(wgt, b.w, acc[7]);
        }
        const int ct = m >> 5, coln = m & 31;
        const int kc = k8 >> 1, kg = k8 & 1;
        const int lane = kg * 32 + coln;
        unsigned short t[8];
        #pragma unroll
        for (int i = 0; i < 8; ++i) t[i] = f2bf(acc[i]);
        *(uint4*)(wfrag + ((size_t)(kc * 4 + ct) * 64 + lane) * 8) = *(const uint4*)t;
        if (kq == 0 && tid < 32) bred[tid] = basis[tid] * fc2_b[m * KB + tid];
        __syncthreads();
        if (kq == 0 && tid == 0) {
            float s = 0.f;
            #pragma unroll
            for (int i = 0; i < 32; ++i) s += bred[i];
            beff[m] = s;
        }
    } else if (bid < 576) {
        const int slot = (bid - 512) * 128 + tid;
        const int lane = slot & 63;
        const int jt   = slot >> 6;
        const int j    = jt * 32 + swap23(lane & 31);
        const int kg   = lane >> 5;
        const float* src = fc1_w + (size_t)j * LATENT + kg * 8;
        const float4 a = *(const float4*)(src);
        const float4 b = *(const float4*)(src + 4);
        unsigned short t[8];
        t[0]=f2bf(a.x); t[1]=f2bf(a.y); t[2]=f2bf(a.z); t[3]=f2bf(a.w);
        t[4]=f2bf(b.x); t[5]=f2bf(b.y); t[6]=f2bf(b.z); t[7]=f2bf(b.w);
        *(uint4*)(f1frag + (size_t)slot * 8) = *(const uint4*)t;
    } else {
        const int jt = tid;
        #pragma unroll
        for (int mp = 0; mp < 32; ++mp) {
            const int lg = mp >> 4, r = mp & 15;
            const int crow = (r & 3) + 8 * (r >> 2) + 4 * lg;
            bh[jt * 32 + mp] = fc1_b[jt * 32 + swap23(crow)];
        }
    }
}

// ---------------------------------------------------------------------------
// Fused (r9 structure + setprio + single-pass parallel tail):
// 256 blocks x 1024 thr (16 waves, 1 blk/CU). Wave = (rt = w&1,
// ctp = (w>>1)&1, ks = w>>2): rows rt*32..+32, cols ctp*64..+64, j-tiles
// ks*32..+32. Per body t: pack hc(t) (computed previous iter), setprio(1),
// 4 main MFMAs, setprio(0), hc <- hT(t+1), prefetch B(t+2)/fv(t+3).
// Tail: each wave writes its 32x64 partial to a PRIVATE 8KB LDS region
// (no races), one barrier, epilogue sums the 4 ks-partials per output.
// ---------------------------------------------------------------------------
__global__ __launch_bounds__(1024, 4) void fused_kernel(
    const float* __restrict__ x,
    const unsigned short* __restrict__ wfrag,
    const unsigned short* __restrict__ f1frag,
    const float* __restrict__ bh,
    const float* __restrict__ beff, float* __restrict__ out)
{
    extern __shared__ char smem[];
    float* bhs  = (float*)smem;              // 132*32 f32 (pad rows zeroed)
    float* part = (float*)(smem + 16896);    // 16 waves x 2048 f32 partials

    const int tid = threadIdx.x;
    const int w   = tid >> 6, l = tid & 63;
    const int l31 = l & 31,  lg = l >> 5;
    const int row0 = blockIdx.x * BM;
    const int rt = w & 1, ctp = (w >> 1) & 1, ks = w >> 2;

    // stage bias table + zero the 4-row overrun pad
    ((float4*)bhs)[tid] = ((const float4*)bh)[tid];
    if (tid < 32) ((float4*)bhs)[1024 + tid] = make_float4(0.f, 0.f, 0.f, 0.f);

    // zfrag: lane l holds z[row0 + rt*32 + l31][lg*8 + r]  (loop-invariant)
    s16x8 zfrag;
    {
        const float* zp = x + (size_t)(row0 + rt * 32 + l31) * XDIM + 2 + lg * 8;
        #pragma unroll
        for (int q = 0; q < 4; ++q) {
            const float2 t = *(const float2*)(zp + 2 * q);
            ((unsigned*)&zfrag)[q] = pack_bf2(t.x, t.y);
        }
    }

    f32x16 acc0, acc1;
    #pragma unroll
    for (int i = 0; i < 16; ++i) { acc0[i] = 0.0f; acc1[i] = 0.0f; }

    // pointers: fv(i) at fvp + i*512; B(i) at bp + i*4096 (kc1 at +2048)
    const unsigned short* fvp = f1frag + ((size_t)(ks * 32) * 64 + l) * 8;
    const unsigned short* bp  = wfrag + ((size_t)(2 * (ks * 32)) * 4 + 2 * ctp) * 512 + l * 8;

    // prologue global loads
    const uint4 fv0 = *(const uint4*)(fvp);
    uint4 fvA = *(const uint4*)(fvp + 512);    // fv(t+1) for even bodies
    uint4 fvB = *(const uint4*)(fvp + 1024);   // fv(t+2) for odd bodies
    s16x8 B0E = *(const s16x8*)(bp);
    s16x8 B1E = *(const s16x8*)(bp + 512);
    s16x8 B2E = *(const s16x8*)(bp + 2048);
    s16x8 B3E = *(const s16x8*)(bp + 2560);
    s16x8 B0O = *(const s16x8*)(bp + 4096);
    s16x8 B1O = *(const s16x8*)(bp + 4096 + 512);
    s16x8 B2O = *(const s16x8*)(bp + 4096 + 2048);
    s16x8 B3O = *(const s16x8*)(bp + 4096 + 2560);

    __syncthreads();   // bhs ready
    const float* bhp = bhs + (ks * 32) * 32 + lg * 16;

    auto hinit = [&](const float* bq) -> f32x16 {
        const float4 c0 = *(const float4*)(bq);
        const float4 c1 = *(const float4*)(bq + 4);
        const float4 c2 = *(const float4*)(bq + 8);
        const float4 c3 = *(const float4*)(bq + 12);
        f32x16 hc;
        hc[0]=c0.x;  hc[1]=c0.y;  hc[2]=c0.z;  hc[3]=c0.w;
        hc[4]=c1.x;  hc[5]=c1.y;  hc[6]=c1.z;  hc[7]=c1.w;
        hc[8]=c2.x;  hc[9]=c2.y;  hc[10]=c2.z; hc[11]=c2.w;
        hc[12]=c3.x; hc[13]=c3.y; hc[14]=c3.z; hc[15]=c3.w;
        return hc;
    };

    // hc(0) ready before the loop
    f32x16 hcA = __builtin_amdgcn_mfma_f32_32x32x16_bf16(
        *(const s16x8*)&fv0, zfrag, hinit(bhp), 0, 0, 0);
    f32x16 hcB;

    for (int t = 0; t < 32; t += 2) {
        // ---- even iter t: pack hc(t), 4 mains (setprio), issue hT(t+1) ----
        {
            unsigned p0[4], p1[4];
            #pragma unroll
            for (int q = 0; q < 4; ++q) {
                p0[q] = pack_bf2(fmaxf(hcA[2*q],   0.f), fmaxf(hcA[2*q+1],   0.f));
                p1[q] = pack_bf2(fmaxf(hcA[8+2*q], 0.f), fmaxf(hcA[8+2*q+1], 0.f));
            }
            __builtin_amdgcn_s_setprio(1);
            acc0 = __builtin_amdgcn_mfma_f32_32x32x16_bf16(*(const s16x8*)p0, B0E, acc0, 0, 0, 0);
            acc1 = __builtin_amdgcn_mfma_f32_32x32x16_bf16(*(const s16x8*)p0, B1E, acc1, 0, 0, 0);
            acc0 = __builtin_amdgcn_mfma_f32_32x32x16_bf16(*(const s16x8*)p1, B2E, acc0, 0, 0, 0);
            acc1 = __builtin_amdgcn_mfma_f32_32x32x16_bf16(*(const s16x8*)p1, B3E, acc1, 0, 0, 0);
            __builtin_amdgcn_s_setprio(0);
        }
        hcB = __builtin_amdgcn_mfma_f32_32x32x16_bf16(
            *(const s16x8*)&fvA, zfrag, hinit(bhp + 32), 0, 0, 0);   // hc(t+1)
        fvA = *(const uint4*)(fvp + 1536);            // fv(t+3)
        B0E = *(const s16x8*)(bp + 8192);             // B(t+2)
        B1E = *(const s16x8*)(bp + 8192 + 512);
        B2E = *(const s16x8*)(bp + 8192 + 2048);
        B3E = *(const s16x8*)(bp + 8192 + 2560);

        // ---- odd iter t+1: pack hc(t+1), 4 mains (setprio), issue hT(t+2) ----
        {
            unsigned p0[4], p1[4];
            #pragma unroll
            for (int q = 0; q < 4; ++q) {
                p0[q] = pack_bf2(fmaxf(hcB[2*q],   0.f), fmaxf(hcB[2*q+1],   0.f));
                p1[q] = pack_bf2(fmaxf(hcB[8+2*q], 0.f), fmaxf(hcB[8+2*q+1], 0.f));
            }
            __builtin_amdgcn_s_setprio(1);
            acc0 = __builtin_amdgcn_mfma_f32_32x32x16_bf16(*(const s16x8*)p0, B0O, acc0, 0, 0, 0);
            acc1 = __builtin_amdgcn_mfma_f32_32x32x16_bf16(*(const s16x8*)p0, B1O, acc1, 0, 0, 0);
            acc0 = __builtin_amdgcn_mfma_f32_32x32x16_bf16(*(const s16x8*)p1, B2O, acc0, 0, 0, 0);
            acc1 = __builtin_amdgcn_mfma_f32_32x32x16_bf16(*(const s16x8*)p1, B3O, acc1, 0, 0, 0);
            __builtin_amdgcn_s_setprio(0);
        }
        hcA = __builtin_amdgcn_mfma_f32_32x32x16_bf16(
            *(const s16x8*)&fvB, zfrag, hinit(bhp + 64), 0, 0, 0);   // hc(t+2)
        fvB = *(const uint4*)(fvp + 2048);            // fv(t+4)
        B0O = *(const s16x8*)(bp + 12288);            // B(t+3)
        B1O = *(const s16x8*)(bp + 12288 + 512);
        B2O = *(const s16x8*)(bp + 12288 + 2048);
        B3O = *(const s16x8*)(bp + 12288 + 2560);

        fvp += 1024; bp += 8192; bhp += 64;
    }

    // ---- tail: parallel partial dump (private region per wave), 1 barrier ----
    {
        float* mypart = part + w * 2048;   // [32 rows][64 cols] local tile
        #pragma unroll
        for (int r = 0; r < 16; ++r) {
            const int rowl = (r & 3) + 8 * (r >> 2) + 4 * lg;
            mypart[rowl * 64 + l31]      = acc0[r];   // local cols 0..31
            mypart[rowl * 64 + 32 + l31] = acc1[r];   // local cols 32..63
        }
    }
    __syncthreads();

    // epilogue: out[b,o] = inp[b] * w[b,o] + w[b,64+o];
    // w[b,c] = beff[c] + sum_ks part[(rt + 2*ctp(c) + 4*ks)][rl*64 + (c&63)]
    {
        const int o = tid & 63, rg = tid >> 6;
        const float belo = beff[o], behi = beff[o + 64];
        #pragma unroll
        for (int i = 0; i < 4; ++i) {
            const int r   = rg * 4 + i;
            const int rt_ = r >> 5, rl = r & 31;
            float wlo = belo, whi = behi;
            #pragma unroll
            for (int ksi = 0; ksi < 4; ++ksi) {
                wlo += part[(rt_ + 4 * ksi) * 2048 + rl * 64 + o];       // ctp=0
                whi += part[(rt_ + 2 + 4 * ksi) * 2048 + rl * 64 + o];   // ctp=1
            }
            const float inp = x[(size_t)(row0 + r) * XDIM];
            out[(size_t)(row0 + r) * OUTF + o] = fmaf(inp, wlo, whi);
        }
    }
}

// ---------------------------------------------------------------------------
extern "C" void kernel_launch(void* const* d_in, const int* in_sizes, int n_in,
                              void* d_out, int out_size, void* d_ws, size_t ws_size,
                              hipStream_t stream) {
    const float* x     = (const float*)d_in[0];
    const float* fc1_w = (const float*)d_in[1];
    const float* fc1_b = (const float*)d_in[2];
    const float* fc2_w = (const float*)d_in[3];
    const float* fc2_b = (const float*)d_in[4];
    const float* dil   = (const float*)d_in[5];
    const float* shf   = (const float*)d_in[6];
    float* out = (float*)d_out;

    // ws: wfrag 1 MB | f1frag 128 KB | beff 512 B | bh 16 KB
    unsigned short* wfrag  = (unsigned short*)d_ws;
    unsigned short* f1frag = wfrag + 524288;
    float*          beff   = (float*)(f1frag + 65536);
    float*          bh     = beff + NM;

    hipFuncSetAttribute((const void*)fused_kernel,
                        hipFuncAttributeMaxDynamicSharedMemorySize, LDS_BYTES);

    precompute_kernel<<<577, 128, 0, stream>>>(x, fc1_w, fc1_b, fc2_w, fc2_b,
                                               dil, shf, wfrag, f1frag, bh, beff);
    fused_kernel<<<BATCH / BM, 1024, LDS_BYTES, stream>>>(x, wfrag, f1frag, bh,
                                                          beff, out);
}